// Round 5
// baseline (447.570 us; speedup 1.0000x reference)
//
#include <hip/hip_runtime.h>
#include <cstdint>
#include <cstddef>

// DeformConv2d B=8 C=256 H=W=64 Cout=256 K=3 s=1 p=1 d=1
// Prepass: weight fp32 -> bf16 into d_ws (1.18 MB, L2-resident).
// Main: fused bilinear im2col (bf16 LDS cols per 32-ch chunk) + MFMA GEMM.
// Grid = (b, ho) = 512 blocks x 512 thr (8 waves). Block tile 256co x 64px.
// Per-thread bilinear tables (px = lane) in NAMED SCALARS (no arrays ->
// nothing can demote to scratch; round-4 lesson): per tap k: oab_k packs
// both corner-row byte offsets (16-bit fields, max 16376B); wa/wb are
// x-selection-folded pair weights. Corner rows loaded as 8B pair-loads.
// K ordering: k = c*9 + kk (matches weight [co][c][kk] flat layout).

#define B_   8
#define C_   256
#define H_   64
#define W_   64
#define CO_  256
#define KK_  9
#define CC   32              // channels per chunk
#define PADK 296             // padded k row (bf16): 592B rows, 16B-aligned

typedef short  short4_t __attribute__((ext_vector_type(4)));
typedef short  short8   __attribute__((ext_vector_type(8)));
typedef float  f32x4    __attribute__((ext_vector_type(4)));
typedef float  f32x2    __attribute__((ext_vector_type(2)));

__device__ inline short f2bf(float f) {   // round-to-nearest-even fp32->bf16
    uint32_t u = __builtin_bit_cast(uint32_t, f);
    u += 0x7FFFu + ((u >> 16) & 1u);
    return (short)(u >> 16);
}

// ---- prepass: weight fp32 -> bf16 ----
__global__ __launch_bounds__(256) void w2bf(const float* __restrict__ w,
                                            short* __restrict__ wb, int n8) {
    const int i = blockIdx.x * 256 + threadIdx.x;
    if (i >= n8) return;
    const f32x4 a = *reinterpret_cast<const f32x4*>(w + i * 8);
    const f32x4 b = *reinterpret_cast<const f32x4*>(w + i * 8 + 4);
    short8 v;
#pragma unroll
    for (int j = 0; j < 4; ++j) { v[j] = f2bf(a[j]); v[j + 4] = f2bf(b[j]); }
    *reinterpret_cast<short8*>(wb + i * 8) = v;
}

// per-tap table: named scalars only
#define TAPD(K) uint32_t oab##K; float wa##K##x, wa##K##y, wb##K##x, wb##K##y;

#define TB(K) { \
    const int ky = K / 3, kx = K % 3; \
    const float offy = offset[(((b * 18) + K * 2 + 0) * 64 + ho) * 64 + lane]; \
    const float offx = offset[(((b * 18) + K * 2 + 1) * 64 + ho) * 64 + lane]; \
    const float py  = (float)(ho - 1 + ky) + offy; \
    const float pxx = (float)(lane - 1 + kx) + offx; \
    const float y0f = floorf(py), x0f = floorf(pxx); \
    const float wy = py - y0f, wx = pxx - x0f; \
    const int y0 = (int)y0f, x0 = (int)x0f; \
    const int y1 = y0 + 1, x1 = x0 + 1; \
    const float vy0 = (y0 >= 0 && y0 < H_) ? 1.f : 0.f; \
    const float vy1 = (y1 >= 0 && y1 < H_) ? 1.f : 0.f; \
    const float vx0 = (x0 >= 0 && x0 < W_) ? 1.f : 0.f; \
    const float vx1 = (x1 >= 0 && x1 < W_) ? 1.f : 0.f; \
    const float wv0 = (1.f - wy) * (1.f - wx) * vy0 * vx0; \
    const float wv1 = (1.f - wy) * wx         * vy0 * vx1; \
    const float wv2 = wy         * (1.f - wx) * vy1 * vx0; \
    const float wv3 = wy         * wx         * vy1 * vx1; \
    const int y0c = min(max(y0, 0), H_ - 1); \
    const int y1c = min(max(y1, 0), H_ - 1); \
    const int x0c = min(max(x0, 0), W_ - 1); \
    const int x1c = min(max(x1, 0), W_ - 1); \
    const int pb  = min(max(x0, 0), W_ - 2); \
    const float sA0 = (x0c == pb)     ? 1.f : 0.f; \
    const float sB0 = (x1c == pb)     ? 1.f : 0.f; \
    const float sA1 = (x0c == pb + 1) ? 1.f : 0.f; \
    const float sB1 = (x1c == pb + 1) ? 1.f : 0.f; \
    wa##K##x = sA0 * wv0 + sB0 * wv1; \
    wa##K##y = sA1 * wv0 + sB1 * wv1; \
    wb##K##x = sA0 * wv2 + sB0 * wv3; \
    wb##K##y = sA1 * wv2 + sB1 * wv3; \
    oab##K = (uint32_t)((y0c * W_ + pb) * 4) | \
             ((uint32_t)((y1c * W_ + pb) * 4) << 16); }

// one interp: channel DC, tap KK, result -> vs{Q}[R]
#define ITP(DC, KK, Q, R) { \
    f32x2 lo, hi; \
    __builtin_memcpy(&lo, xp##DC + (oab##KK & 0xFFFFu), 8); \
    __builtin_memcpy(&hi, xp##DC + (oab##KK >> 16), 8); \
    vs##Q[R] = f2bf(wa##KK##x * lo[0] + wa##KK##y * lo[1] + \
                    wb##KK##x * hi[0] + wb##KK##y * hi[1]); }

#define MM(MT) { \
    const short8 af = *reinterpret_cast<const short8*>(wrow##MT + kglob); \
    acc##MT##0 = __builtin_amdgcn_mfma_f32_16x16x32_bf16(af, bfA, acc##MT##0, 0, 0, 0); \
    acc##MT##1 = __builtin_amdgcn_mfma_f32_16x16x32_bf16(af, bfB, acc##MT##1, 0, 0, 0); }

#define EP(MT) { \
    _Pragma("unroll") \
    for (int r = 0; r < 4; ++r) { \
        const int co = co0 + MT * 16 + r0 + r; \
        const float bv = bias[co]; \
        float* orow = out + ((size_t)(b * CO_ + co) * H_ + ho) * W_; \
        orow[px0 + m_l]      = acc##MT##0[r] + bv; \
        orow[px0 + 16 + m_l] = acc##MT##1[r] + bv; } }

__global__ __launch_bounds__(512, 4) void dcn_mfma(
    const float* __restrict__ x,
    const float* __restrict__ offset,
    const short* __restrict__ wbf,     // bf16 weight [256][2304]
    const float* __restrict__ bias,
    float* __restrict__ out)
{
    __shared__ short cols[64 * PADK];   // [px][k] bf16 columns, one chunk

    const int bid = blockIdx.x;         // 512 = 64 * 8
    const int ho  = bid & 63;
    const int b   = bid >> 6;

    const int t    = threadIdx.x;
    const int lane = t & 63;            // px = wo
    const int wave = t >> 6;

    // ---- per-thread bilinear tables (px = lane), named scalars ----
    TAPD(0) TAPD(1) TAPD(2) TAPD(3) TAPD(4) TAPD(5) TAPD(6) TAPD(7) TAPD(8)
    TB(0) TB(1) TB(2) TB(3) TB(4) TB(5) TB(6) TB(7) TB(8)

    f32x4 acc00 = {0.f,0.f,0.f,0.f}, acc01 = {0.f,0.f,0.f,0.f};
    f32x4 acc10 = {0.f,0.f,0.f,0.f}, acc11 = {0.f,0.f,0.f,0.f};
    f32x4 acc20 = {0.f,0.f,0.f,0.f}, acc21 = {0.f,0.f,0.f,0.f};
    f32x4 acc30 = {0.f,0.f,0.f,0.f}, acc31 = {0.f,0.f,0.f,0.f};

    const int wm = wave >> 1;          // co-64 group
    const int wn = wave & 1;           // px-32 group
    const int co0 = __builtin_amdgcn_readfirstlane(wm * 64);
    const int px0 = __builtin_amdgcn_readfirstlane(wn * 32);
    const int m_l = lane & 15;         // row/col index within 16x16 fragment
    const int k_l = (lane >> 4) << 3;  // 8 contiguous k per lane

    const short* wrow0 = wbf + (size_t)(co0 +  0 + m_l) * (C_ * KK_);
    const short* wrow1 = wbf + (size_t)(co0 + 16 + m_l) * (C_ * KK_);
    const short* wrow2 = wbf + (size_t)(co0 + 32 + m_l) * (C_ * KK_);
    const short* wrow3 = wbf + (size_t)(co0 + 48 + m_l) * (C_ * KK_);

    for (int c0 = 0; c0 < C_; c0 += CC) {
        // ---- stage: thread covers px=lane, channels c0+4*wave..+3 ----
        const char* xp0 = (const char*)(x + ((size_t)(b * C_ + c0 + 4 * wave + 0) << 12));
        const char* xp1 = (const char*)(x + ((size_t)(b * C_ + c0 + 4 * wave + 1) << 12));
        const char* xp2 = (const char*)(x + ((size_t)(b * C_ + c0 + 4 * wave + 2) << 12));
        const char* xp3 = (const char*)(x + ((size_t)(b * C_ + c0 + 4 * wave + 3) << 12));

        short4_t vs0, vs1, vs2, vs3, vs4, vs5, vs6, vs7, vs8;
        // idx = dc*9+kk -> vs[idx/4][idx%4]
        ITP(0,0,0,0) ITP(0,1,0,1) ITP(0,2,0,2) ITP(0,3,0,3)
        ITP(0,4,1,0) ITP(0,5,1,1) ITP(0,6,1,2) ITP(0,7,1,3)
        ITP(0,8,2,0)
        ITP(1,0,2,1) ITP(1,1,2,2) ITP(1,2,2,3)
        ITP(1,3,3,0) ITP(1,4,3,1) ITP(1,5,3,2) ITP(1,6,3,3)
        ITP(1,7,4,0) ITP(1,8,4,1)
        ITP(2,0,4,2) ITP(2,1,4,3)
        ITP(2,2,5,0) ITP(2,3,5,1) ITP(2,4,5,2) ITP(2,5,5,3)
        ITP(2,6,6,0) ITP(2,7,6,1) ITP(2,8,6,2)
        ITP(3,0,6,3)
        ITP(3,1,7,0) ITP(3,2,7,1) ITP(3,3,7,2) ITP(3,4,7,3)
        ITP(3,5,8,0) ITP(3,6,8,1) ITP(3,7,8,2) ITP(3,8,8,3)

        short* crow = &cols[lane * PADK + wave * 36];
        *reinterpret_cast<short4_t*>(crow +  0) = vs0;
        *reinterpret_cast<short4_t*>(crow +  4) = vs1;
        *reinterpret_cast<short4_t*>(crow +  8) = vs2;
        *reinterpret_cast<short4_t*>(crow + 12) = vs3;
        *reinterpret_cast<short4_t*>(crow + 16) = vs4;
        *reinterpret_cast<short4_t*>(crow + 20) = vs5;
        *reinterpret_cast<short4_t*>(crow + 24) = vs6;
        *reinterpret_cast<short4_t*>(crow + 28) = vs7;
        *reinterpret_cast<short4_t*>(crow + 32) = vs8;
        __syncthreads();

        // ---- MFMA over 9 k-steps ----
#pragma unroll
        for (int s = 0; s < 9; ++s) {
            const int krow = s * 32 + k_l;
            const short8 bfA = *reinterpret_cast<const short8*>(
                &cols[(px0 + m_l) * PADK + krow]);
            const short8 bfB = *reinterpret_cast<const short8*>(
                &cols[(px0 + 16 + m_l) * PADK + krow]);
            const int kglob = c0 * 9 + krow;
            MM(0) MM(1) MM(2) MM(3)
        }
        __syncthreads();
    }

    // ---- epilogue: D mapping col=lane&15 (n=px), row=(lane>>4)*4+r (m=co) ----
    const int r0 = (lane >> 4) << 2;
    EP(0) EP(1) EP(2) EP(3)
}

extern "C" void kernel_launch(void* const* d_in, const int* in_sizes, int n_in,
                              void* d_out, int out_size, void* d_ws, size_t ws_size,
                              hipStream_t stream) {
    const float* x      = (const float*)d_in[0];
    const float* offset = (const float*)d_in[1];
    const float* weight = (const float*)d_in[2];
    const float* bias   = (const float*)d_in[3];
    float* out = (float*)d_out;
    short* wbf = (short*)d_ws;          // 589824 bf16 = 1.18 MB
    (void)in_sizes; (void)n_in; (void)out_size; (void)ws_size;

    const int n8 = (CO_ * C_ * KK_) / 8;        // 73728 short8 groups
    hipLaunchKernelGGL(w2bf, dim3((n8 + 255) / 256), dim3(256), 0, stream,
                       weight, wbf, n8);
    hipLaunchKernelGGL(dcn_mfma, dim3(64 * B_), dim3(512), 0, stream,
                       x, offset, wbf, bias, out);
}

// Round 6
// 292.766 us; speedup vs baseline: 1.5288x; 1.5288x over previous
//
#include <hip/hip_runtime.h>
#include <cstdint>
#include <cstddef>

// DeformConv2d B=8 C=256 H=W=64 Cout=256 K=3 s=1 p=1 d=1
// Prepass: weight fp32 -> bf16 into d_ws (1.18 MB, L2-resident).
// Main: fused bilinear im2col (bf16 LDS cols per 32-ch chunk) + MFMA GEMM.
// Grid = (b, ho) = 512 blocks x 512 thr (8 waves). Block tile 256co x 64px.
// Bilinear tables in LDS (round-3 home, no spill) in PACKED PAIR form:
// per (kk,px): oab u32 = two corner-row byte offsets (16b fields),
// wv f32x4 = x-selection-folded pair weights. Interp = 2 LDS reads +
// 2 x 8B global pair-loads (x1 = x0+1 contiguous).
// launch_bounds(512,2): VGPR cap >= 128 (round-4/5 spills were the 64-cap).
// K ordering: k = c*9 + kk (matches weight [co][c][kk] flat layout).

#define B_   8
#define C_   256
#define H_   64
#define W_   64
#define CO_  256
#define KK_  9
#define CC   32              // channels per chunk
#define PADK 296             // padded k row (bf16): 592B rows, 16B-aligned

typedef short  short4_t __attribute__((ext_vector_type(4)));
typedef short  short8   __attribute__((ext_vector_type(8)));
typedef float  f32x4    __attribute__((ext_vector_type(4)));
typedef float  f32x2    __attribute__((ext_vector_type(2)));

__device__ inline short f2bf(float f) {   // round-to-nearest-even fp32->bf16
    uint32_t u = __builtin_bit_cast(uint32_t, f);
    u += 0x7FFFu + ((u >> 16) & 1u);
    return (short)(u >> 16);
}

// ---- prepass: weight fp32 -> bf16 ----
__global__ __launch_bounds__(256) void w2bf(const float* __restrict__ w,
                                            short* __restrict__ wb, int n8) {
    const int i = blockIdx.x * 256 + threadIdx.x;
    if (i >= n8) return;
    const f32x4 a = *reinterpret_cast<const f32x4*>(w + i * 8);
    const f32x4 b = *reinterpret_cast<const f32x4*>(w + i * 8 + 4);
    short8 v;
#pragma unroll
    for (int j = 0; j < 4; ++j) { v[j] = f2bf(a[j]); v[j + 4] = f2bf(b[j]); }
    *reinterpret_cast<short8*>(wb + i * 8) = v;
}

__global__ __launch_bounds__(512, 2) void dcn_mfma(
    const float* __restrict__ x,
    const float* __restrict__ offset,
    const short* __restrict__ wbf,     // bf16 weight [256][2304]
    const float* __restrict__ bias,
    float* __restrict__ out)
{
    __shared__ uint32_t t_oab[KK_ * 64];   // packed pair offsets
    __shared__ f32x4    t_wv[KK_ * 64];    // folded pair weights
    __shared__ short    cols[64 * PADK];   // [px][k] bf16 columns, one chunk

    const int bid = blockIdx.x;            // 512 = 64 * 8
    const int ho  = bid & 63;
    const int b   = bid >> 6;

    const int t    = threadIdx.x;
    const int lane = t & 63;               // px = wo
    const int wave = t >> 6;

    // ---- bilinear tables: one entry per (kk, wo) ----
    for (int e = t; e < KK_ * 64; e += 512) {
        const int kk = e >> 6;
        const int wo = e & 63;
        const int ky = kk / 3, kx = kk % 3;
        const float offy = offset[(((b * 18) + kk * 2 + 0) * 64 + ho) * 64 + wo];
        const float offx = offset[(((b * 18) + kk * 2 + 1) * 64 + ho) * 64 + wo];
        const float py  = (float)(ho - 1 + ky) + offy;
        const float pxx = (float)(wo - 1 + kx) + offx;
        const float y0f = floorf(py), x0f = floorf(pxx);
        const float wy = py - y0f, wx = pxx - x0f;
        const int y0 = (int)y0f, x0 = (int)x0f;
        const int y1 = y0 + 1,   x1 = x0 + 1;
        const float vy0 = (y0 >= 0 && y0 < H_) ? 1.f : 0.f;
        const float vy1 = (y1 >= 0 && y1 < H_) ? 1.f : 0.f;
        const float vx0 = (x0 >= 0 && x0 < W_) ? 1.f : 0.f;
        const float vx1 = (x1 >= 0 && x1 < W_) ? 1.f : 0.f;
        const float wv0 = (1.f - wy) * (1.f - wx) * vy0 * vx0;
        const float wv1 = (1.f - wy) * wx         * vy0 * vx1;
        const float wv2 = wy         * (1.f - wx) * vy1 * vx0;
        const float wv3 = wy         * wx         * vy1 * vx1;
        const int y0c = min(max(y0, 0), H_ - 1);
        const int y1c = min(max(y1, 0), H_ - 1);
        const int x0c = min(max(x0, 0), W_ - 1);
        const int x1c = min(max(x1, 0), W_ - 1);
        const int pb  = min(max(x0, 0), W_ - 2);   // pair base (covers pb, pb+1)
        const float sA0 = (x0c == pb)     ? 1.f : 0.f;
        const float sB0 = (x1c == pb)     ? 1.f : 0.f;
        const float sA1 = (x0c == pb + 1) ? 1.f : 0.f;
        const float sB1 = (x1c == pb + 1) ? 1.f : 0.f;
        f32x4 wv;
        wv[0] = sA0 * wv0 + sB0 * wv1;   // lo[0] weight
        wv[1] = sA1 * wv0 + sB1 * wv1;   // lo[1] weight
        wv[2] = sA0 * wv2 + sB0 * wv3;   // hi[0] weight
        wv[3] = sA1 * wv2 + sB1 * wv3;   // hi[1] weight
        t_oab[e] = (uint32_t)((y0c * W_ + pb) * 4) |
                   ((uint32_t)((y1c * W_ + pb) * 4) << 16);
        t_wv[e] = wv;
    }
    __syncthreads();

    f32x4 acc[4][2];   // [mt co][nt px]
#pragma unroll
    for (int i = 0; i < 4; ++i) { acc[i][0] = (f32x4)0.f; acc[i][1] = (f32x4)0.f; }

    const int wm = wave >> 1;          // co-64 group
    const int wn = wave & 1;           // px-32 group
    const int co0 = __builtin_amdgcn_readfirstlane(wm * 64);
    const int px0 = __builtin_amdgcn_readfirstlane(wn * 32);
    const int wqs = __builtin_amdgcn_readfirstlane(wave);   // scalar wave idx
    const int m_l = lane & 15;         // row/col index within 16x16 fragment
    const int k_l = (lane >> 4) << 3;  // 8 contiguous k per lane

    const short* wrow[4];
#pragma unroll
    for (int mt = 0; mt < 4; ++mt)
        wrow[mt] = wbf + (size_t)(co0 + mt * 16 + m_l) * (C_ * KK_);

    for (int c0 = 0; c0 < C_; c0 += CC) {
        // ---- stage: thread covers px=lane, channels c0+4*wave..+3 ----
        const char* xp[4];
#pragma unroll
        for (int dc = 0; dc < 4; ++dc)
            xp[dc] = (const char*)(x + ((size_t)(b * C_ + c0 + 4 * wqs + dc) << 12));

#pragma unroll
        for (int j = 0; j < 9; ++j) {            // 9 quads of 4 consecutive k
            short4_t vs;
#pragma unroll
            for (int jj = 0; jj < 4; ++jj) {
                const int idx = j * 4 + jj;      // 0..35 (static)
                const int dc  = idx / 9;         // static
                const int kk  = idx % 9;         // static
                const uint32_t oab = t_oab[kk * 64 + lane];
                const f32x4    wv  = t_wv[kk * 64 + lane];
                f32x2 lo, hi;
                __builtin_memcpy(&lo, xp[dc] + (oab & 0xFFFFu), 8);
                __builtin_memcpy(&hi, xp[dc] + (oab >> 16), 8);
                vs[jj] = f2bf(wv[0] * lo[0] + wv[1] * lo[1] +
                              wv[2] * hi[0] + wv[3] * hi[1]);
            }
            *reinterpret_cast<short4_t*>(&cols[lane * PADK + (wave * 9 + j) * 4]) = vs;
        }
        __syncthreads();

        // ---- MFMA over 9 k-steps ----
#pragma unroll
        for (int s = 0; s < 9; ++s) {
            const int krow = s * 32 + k_l;
            const short8 bfA = *reinterpret_cast<const short8*>(
                &cols[(px0 + m_l) * PADK + krow]);
            const short8 bfB = *reinterpret_cast<const short8*>(
                &cols[(px0 + 16 + m_l) * PADK + krow]);
            const int kglob = c0 * 9 + krow;
#pragma unroll
            for (int mt = 0; mt < 4; ++mt) {
                const short8 af = *reinterpret_cast<const short8*>(wrow[mt] + kglob);
                acc[mt][0] = __builtin_amdgcn_mfma_f32_16x16x32_bf16(
                    af, bfA, acc[mt][0], 0, 0, 0);
                acc[mt][1] = __builtin_amdgcn_mfma_f32_16x16x32_bf16(
                    af, bfB, acc[mt][1], 0, 0, 0);
            }
        }
        __syncthreads();
    }

    // ---- epilogue: D mapping col=lane&15 (n=px), row=(lane>>4)*4+r (m=co) ----
    const int r0 = (lane >> 4) << 2;
#pragma unroll
    for (int mt = 0; mt < 4; ++mt) {
#pragma unroll
        for (int r = 0; r < 4; ++r) {
            const int co = co0 + mt * 16 + r0 + r;
            const float bv = bias[co];
            float* orow = out + ((size_t)(b * CO_ + co) * H_ + ho) * W_;
            orow[px0 + m_l]      = acc[mt][0][r] + bv;
            orow[px0 + 16 + m_l] = acc[mt][1][r] + bv;
        }
    }
}

extern "C" void kernel_launch(void* const* d_in, const int* in_sizes, int n_in,
                              void* d_out, int out_size, void* d_ws, size_t ws_size,
                              hipStream_t stream) {
    const float* x      = (const float*)d_in[0];
    const float* offset = (const float*)d_in[1];
    const float* weight = (const float*)d_in[2];
    const float* bias   = (const float*)d_in[3];
    float* out = (float*)d_out;
    short* wbf = (short*)d_ws;          // 589824 bf16 = 1.18 MB
    (void)in_sizes; (void)n_in; (void)out_size; (void)ws_size;

    const int n8 = (CO_ * C_ * KK_) / 8;        // 73728 short8 groups
    hipLaunchKernelGGL(w2bf, dim3((n8 + 255) / 256), dim3(256), 0, stream,
                       weight, wbf, n8);
    hipLaunchKernelGGL(dcn_mfma, dim3(64 * B_), dim3(512), 0, stream,
                       x, offset, wbf, bias, out);
}